// Round 20
// baseline (184.866 us; speedup 1.0000x reference)
//
#include <hip/hip_runtime.h>
#include <stdint.h>

#define NROWS 32768
#define DIMS  256
#define KCB   1024
#define BM 128
#define BN 128
#define GY (KCB/BN)   // 8 code-blocks
#define MARGIN 0.25f  // flag threshold AND rescue candidate window

typedef _Float16 half8   __attribute__((ext_vector_type(8)));
typedef float    f32x4   __attribute__((ext_vector_type(4)));
typedef short    short4v __attribute__((ext_vector_type(4)));
typedef short    short8v __attribute__((ext_vector_type(8)));

// async global->LDS, 16B per lane; LDS dest = wave-uniform base + lane*16
__device__ __forceinline__ void gload_lds16(const void* g, void* l) {
    __builtin_amdgcn_global_load_lds(
        (const __attribute__((address_space(1))) uint32_t*)g,
        (__attribute__((address_space(3))) uint32_t*)l, 16, 0, 0);
}

__device__ __forceinline__ short f16h(float v) {
    _Float16 hh = (_Float16)v;
    return __builtin_bit_cast(short, hh);
}

// ---- merged splitter: X and E -> fragment-ordered f16 + he2 --------------
__global__ __launch_bounds__(256) void split_all(
    const float* __restrict__ x, short* __restrict__ Xh,
    const float* __restrict__ embed, short* __restrict__ Eh,
    float* __restrict__ he2)
{
    if (blockIdx.x < 4096) {
        int T = blockIdx.x * 256 + threadIdx.x;
        int l = T & 63, c = (T >> 6) & 7, G = T >> 9;
        int row = G * 16 + (l & 15);
        int kb  = c * 32 + (l >> 4) * 8;
        const f32x4* src = (const f32x4*)(x + (size_t)row * DIMS + kb);
        f32x4 a = src[0], b = src[1];
        short8v h;
        #pragma unroll
        for (int e = 0; e < 4; ++e) { h[e] = f16h(a[e]); h[4 + e] = f16h(b[e]); }
        *(short8v*)(Xh + (size_t)G * 4096 + c * 512 + l * 8) = h;
    } else {
        int r = (blockIdx.x - 4096) * 4 + (threadIdx.x >> 6);   // code 0..1023
        int l = threadIdx.x & 63;
        f32x4 v = ((const f32x4*)(embed + (size_t)r * DIMS))[l];
        float s = v[0]*v[0] + v[1]*v[1] + v[2]*v[2] + v[3]*v[3];
        #pragma unroll
        for (int off = 32; off > 0; off >>= 1) s += __shfl_down(s, off, 64);
        if (l == 0) he2[r] = 0.5f * s;
        int G = r >> 4, cc = l >> 3;
        int fl = (r & 15) + 16 * ((l >> 1) & 3);
        size_t base = (size_t)G * 4096 + cc * 512 + fl * 8 + (l & 1) * 4;
        short4v h;
        #pragma unroll
        for (int e = 0; e < 4; ++e) h[e] = f16h(v[e]);
        *(short4v*)(Eh + base) = h;
    }
}

// ---- 16-lane-group exact dot (verified rounds 11-19) ---------------------
__device__ __forceinline__ float dot16(f32x4 xa, f32x4 xb, f32x4 xc, f32x4 xd,
                                       const float* __restrict__ erow, int q) {
    const f32x4* er = (const f32x4*)(erow + q * 16);
    f32x4 ea = er[0], eb = er[1], ec = er[2], ed = er[3];
    float s = xa[0] * ea[0];
    s = fmaf(xa[1], ea[1], s); s = fmaf(xa[2], ea[2], s); s = fmaf(xa[3], ea[3], s);
    s = fmaf(xb[0], eb[0], s); s = fmaf(xb[1], eb[1], s);
    s = fmaf(xb[2], eb[2], s); s = fmaf(xb[3], eb[3], s);
    s = fmaf(xc[0], ec[0], s); s = fmaf(xc[1], ec[1], s);
    s = fmaf(xc[2], ec[2], s); s = fmaf(xc[3], ec[3], s);
    s = fmaf(xd[0], ed[0], s); s = fmaf(xd[1], ed[1], s);
    s = fmaf(xd[2], ed[2], s); s = fmaf(xd[3], ed[3], s);
    s += __shfl_xor(s, 1, 64);
    s += __shfl_xor(s, 2, 64);
    s += __shfl_xor(s, 4, 64);
    s += __shfl_xor(s, 8, 64);
    return s;
}

// ---- approx GEMM + argmax + LAST-BLOCK fused combine/gather/rescue -------
// Main loop + epilogue byte-identical to r19 (37us path). After part write:
// device-fence + panel counter; the 8th (last) block of a panel inlines the
// verified combine+gather+rescue for its 128 rows (output independent of
// which block wins -> deterministic).
__global__ __launch_bounds__(256, 4) void vq_mfma(
    const short* __restrict__ Xh, const short* __restrict__ Eh,
    const float* __restrict__ he2, float4* __restrict__ part,
    const float* __restrict__ x, const float* __restrict__ embed,
    float* __restrict__ outq, float* __restrict__ outi,
    int* __restrict__ panelCnt)
{
    __shared__ char lds[32768];
    __shared__ int  idxS[BM];
    __shared__ int  flagL[BM];
    __shared__ int  flagN;
    __shared__ int  lastFlag;

    const int t = threadIdx.x, lane = t & 63, w = t >> 6;
    const int wm = w >> 1, wn = w & 1;
    const int lhi = lane >> 4, c15 = lane & 15;
    const int sid = blockIdx.x;
    const int xcd = sid & 7, j = sid >> 3;
    const int rb = xcd * 32 + (j >> 3), cb = j & 7;
    const int rowBase = rb * BM, colBase = cb * BN;

    const char* gA[4];
    const char* gB[4];
    #pragma unroll
    for (int m = 0; m < 4; ++m)
        gA[m] = (const char*)Xh + (size_t)(rb * 8 + wm * 4 + m) * 8192 + lane * 16;
    #pragma unroll
    for (int n = 0; n < 4; ++n)
        gB[n] = (const char*)Eh + (size_t)(cb * 8 + wn * 4 + n) * 8192 + lane * 16;
    char* lw = lds + w * 8192;

    f32x4 acc[4][4];
    #pragma unroll
    for (int m = 0; m < 4; ++m)
        #pragma unroll
        for (int n = 0; n < 4; ++n) acc[m][n] = (f32x4){0.f, 0.f, 0.f, 0.f};

    #pragma unroll
    for (int m = 0; m < 4; ++m) gload_lds16(gA[m], lw + m * 1024);
    #pragma unroll
    for (int n = 0; n < 4; ++n) gload_lds16(gB[n], lw + 4096 + n * 1024);

    #pragma unroll
    for (int c = 0; c < 8; ++c) {
        asm volatile("s_waitcnt vmcnt(0)" ::: "memory");   // my chunk arrived
        __builtin_amdgcn_sched_barrier(0);

        half8 A[4], B[4];
        #pragma unroll
        for (int m = 0; m < 4; ++m)
            A[m] = *(const half8*)(lw + m * 1024 + lane * 16);
        #pragma unroll
        for (int n = 0; n < 4; ++n)
            B[n] = *(const half8*)(lw + 4096 + n * 1024 + lane * 16);
        asm volatile("s_waitcnt lgkmcnt(0)" ::: "memory"); // regs loaded
        __builtin_amdgcn_sched_barrier(0);                 // rule #18 fence

        if (c < 7) {                                       // refill in place
            #pragma unroll
            for (int m = 0; m < 4; ++m)
                gload_lds16(gA[m] + (c + 1) * 1024, lw + m * 1024);
            #pragma unroll
            for (int n = 0; n < 4; ++n)
                gload_lds16(gB[n] + (c + 1) * 1024, lw + 4096 + n * 1024);
        }
        __builtin_amdgcn_sched_barrier(0);                 // loads before MFMA

        __builtin_amdgcn_s_setprio(1);
        #pragma unroll
        for (int m = 0; m < 4; ++m)
            #pragma unroll
            for (int n = 0; n < 4; ++n)
                acc[m][n] = __builtin_amdgcn_mfma_f32_16x16x32_f16(A[m], B[n], acc[m][n], 0, 0, 0);
        __builtin_amdgcn_s_setprio(0);
    }

    // ---- epilogue: LDS-assisted best/2nd argmax (verified r16-r19) -------
    __syncthreads();   // all waves done with staging LDS -> safe to alias
    float* S1 = (float*)lds;              // [128][17] f32  (8704 B)
    int*   I1 = (int*)(lds + 8704);       // [128][17] i32
    float* S2 = (float*)(lds + 17408);    // [128][17] f32  (total 26112 B)

    float h2[4];
    #pragma unroll
    for (int n = 0; n < 4; ++n) h2[n] = he2[colBase + 64 * wn + 16 * n + c15];
    const int colg0 = colBase + 64 * wn + c15;

    #pragma unroll
    for (int m = 0; m < 4; ++m) {
        #pragma unroll
        for (int reg = 0; reg < 4; ++reg) {
            float b1 = acc[m][0][reg] - h2[0];
            int   i1 = colg0;
            float b2 = -3.4e38f;
            #pragma unroll
            for (int n = 1; n < 4; ++n) {
                float s = acc[m][n][reg] - h2[n];
                if (s > b1) { b2 = b1; b1 = s; i1 = colg0 + 16 * n; }
                else        { b2 = fmaxf(b2, s); }
            }
            {
                float ob1 = __shfl_xor(b1, 1, 64);
                int   oi1 = __shfl_xor(i1, 1, 64);
                float ob2 = __shfl_xor(b2, 1, 64);
                if (ob1 > b1 || (ob1 == b1 && oi1 < i1)) {
                    b2 = fmaxf(b1, ob2); b1 = ob1; i1 = oi1;
                } else {
                    b2 = fmaxf(b2, ob1);
                }
            }
            if ((c15 & 1) == 0) {
                int row  = 64 * wm + 16 * m + 4 * lhi + reg;   // 0..127
                int slot = wn * 8 + (c15 >> 1);                // 0..15
                S1[row * 17 + slot] = b1;
                I1[row * 17 + slot] = i1;
                S2[row * 17 + slot] = b2;
            }
        }
    }
    __syncthreads();

    if (t < BM) {
        float b1 = S1[t * 17]; int i1 = I1[t * 17]; float b2 = S2[t * 17];
        #pragma unroll
        for (int s = 1; s < 16; ++s) {
            float c1 = S1[t * 17 + s]; int j1 = I1[t * 17 + s];
            float c2 = S2[t * 17 + s];
            if (c1 > b1 || (c1 == b1 && j1 < i1)) { b2 = fmaxf(b1, c2); b1 = c1; i1 = j1; }
            else                                  { b2 = fmaxf(b2, c1); }
        }
        part[(size_t)(rowBase + t) * GY + cb] =
            make_float4(b1, __int_as_float(i1), b2, 0.f);
    }

    // ---- last-block detection (device-scope release/acquire) -------------
    __syncthreads();                      // part stores drained to L2
    if (t == 0) {
        __threadfence();                  // release: make panel writes visible
        int old = atomicAdd(&panelCnt[rb], 1);
        lastFlag = (old == GY - 1);
    }
    __syncthreads();
    if (!lastFlag) return;
    __threadfence();                      // acquire before reading others' part

    // ---- fused combine: merge 8 partials per row (verified logic) --------
    if (t == 0) flagN = 0;
    __syncthreads();
    if (t < BM) {
        const int row = rowBase + t;
        float4 p = part[(size_t)row * GY];
        float b1 = p.x; int i1 = __float_as_int(p.y); float b2 = p.z;
        #pragma unroll
        for (int g = 1; g < GY; ++g) {
            float4 q = part[(size_t)row * GY + g];
            float c1 = q.x; int j1 = __float_as_int(q.y); float c2 = q.z;
            if (c1 > b1 || (c1 == b1 && j1 < i1)) { b2 = fmaxf(b1, c2); b1 = c1; i1 = j1; }
            else                                  { b2 = fmaxf(b2, c1); }
        }
        idxS[t] = i1;
        outi[row] = (float)i1;
        if (b1 - b2 < MARGIN) {
            int s = atomicAdd(&flagN, 1);
            flagL[s] = t;
        }
    }
    __syncthreads();

    // ---- gather: quantize[r][:] = embed[idx[r]][:] -----------------------
    #pragma unroll
    for (int qq = 0; qq < (BM * 64) / 256; ++qq) {         // 32 iters
        int f = t + 256 * qq;
        int r = f >> 6, c4 = f & 63;
        int e = idxS[r];
        f32x4 v = *(const f32x4*)(embed + (size_t)e * DIMS + c4 * 4);
        *(f32x4*)(outq + (size_t)(rowBase + r) * DIMS + c4 * 4) = v;
    }
    __syncthreads();   // drain approx gather writes before rescue overwrites

    // ---- exact rescue: one wave per flagged row (verified r11-r19) -------
    const int nf = flagN;
    const int q = c15, pgrp = lhi;
    for (int it = w; it < nf; it += 4) {
        int rrow = rowBase + flagL[it];
        const f32x4* xr = (const f32x4*)(x + (size_t)rrow * DIMS + q * 16);
        f32x4 xa = xr[0], xb = xr[1], xc = xr[2], xd = xr[3];

        float4 pc[GY];
        #pragma unroll
        for (int g = 0; g < GY; ++g) pc[g] = part[(size_t)rrow * GY + g];
        float B1 = pc[0].x;
        #pragma unroll
        for (int g = 1; g < GY; ++g) B1 = fmaxf(B1, pc[g].x);
        const float T = B1 - MARGIN;

        float wb = -3.4e38f; int wi = 0x7fffffff;
        #pragma unroll
        for (int g = 0; g < GY; ++g) {
            if (pc[g].z >= T) {
                #pragma unroll 2
                for (int i = 0; i < BN / 4; ++i) {
                    int code = g * BN + i * 4 + pgrp;
                    float s = dot16(xa, xb, xc, xd,
                                    embed + (size_t)code * DIMS, q) - he2[code];
                    if (s > wb || (s == wb && code < wi)) { wb = s; wi = code; }
                }
            } else if (pc[g].x >= T) {
                int code = __float_as_int(pc[g].y);
                float s = dot16(xa, xb, xc, xd,
                                embed + (size_t)code * DIMS, q) - he2[code];
                if (s > wb || (s == wb && code < wi)) { wb = s; wi = code; }
            }
        }
        #pragma unroll
        for (int msk = 16; msk <= 32; msk <<= 1) {
            float ob = __shfl_xor(wb, msk, 64);
            int   oi = __shfl_xor(wi, msk, 64);
            if (ob > wb || (ob == wb && oi < wi)) { wb = ob; wi = oi; }
        }
        f32x4 v = ((const f32x4*)(embed + (size_t)wi * DIMS))[lane];
        ((f32x4*)(outq + (size_t)rrow * DIMS))[lane] = v;
        if (lane == 0) outi[rrow] = (float)wi;
    }
}

extern "C" void kernel_launch(void* const* d_in, const int* in_sizes, int n_in,
                              void* d_out, int out_size, void* d_ws, size_t ws_size,
                              hipStream_t stream) {
    const float* x     = (const float*)d_in[0];
    const float* embed = (const float*)d_in[1];
    char* ws = (char*)d_ws;
    float*  he2      = (float*)ws;                          // 4 KB
    int*    panelCnt = (int*)(ws + 4096);                   // 1 KB (256 ints)
    float4* part     = (float4*)(ws + 8192);                // 4 MB
    short*  Xh       = (short*)(ws + 8192 + 4194304);       // 16.8 MB
    short*  Eh       = (short*)(ws + 8192 + 4194304 + 16777216);  // 512 KB
    float*  out  = (float*)d_out;
    float*  outi = out + (size_t)NROWS * DIMS;

    hipMemsetAsync(panelCnt, 0, 256 * sizeof(int), stream);
    split_all<<<4352, 256, 0, stream>>>(x, Xh, embed, Eh, he2);
    vq_mfma<<<(NROWS / BM) * GY, 256, 0, stream>>>(Xh, Eh, he2, part,
                                                   x, embed, out, outi, panelCnt);
}

// Round 21
// 72.492 us; speedup vs baseline: 2.5502x; 2.5502x over previous
//
#include <hip/hip_runtime.h>
#include <stdint.h>

#define NROWS 32768
#define DIMS  256
#define KCB   1024
#define BM 128
#define BN 128
#define GY (KCB/BN)   // 8 code-blocks
#define MARGIN 0.25f  // flag threshold AND rescue candidate window
#define CROWS 16      // rows per combine block

typedef _Float16 half8   __attribute__((ext_vector_type(8)));
typedef float    f32x4   __attribute__((ext_vector_type(4)));
typedef short    short4v __attribute__((ext_vector_type(4)));
typedef short    short8v __attribute__((ext_vector_type(8)));

// async global->LDS, 16B per lane; LDS dest = wave-uniform base + lane*16
__device__ __forceinline__ void gload_lds16(const void* g, void* l) {
    __builtin_amdgcn_global_load_lds(
        (const __attribute__((address_space(1))) uint32_t*)g,
        (__attribute__((address_space(3))) uint32_t*)l, 16, 0, 0);
}

__device__ __forceinline__ short f16h(float v) {
    _Float16 hh = (_Float16)v;
    return __builtin_bit_cast(short, hh);
}

// ---- merged splitter: X and E -> fragment-ordered f16 + he2 --------------
__global__ __launch_bounds__(256) void split_all(
    const float* __restrict__ x, short* __restrict__ Xh,
    const float* __restrict__ embed, short* __restrict__ Eh,
    float* __restrict__ he2)
{
    if (blockIdx.x < 4096) {
        int T = blockIdx.x * 256 + threadIdx.x;
        int l = T & 63, c = (T >> 6) & 7, G = T >> 9;
        int row = G * 16 + (l & 15);
        int kb  = c * 32 + (l >> 4) * 8;
        const f32x4* src = (const f32x4*)(x + (size_t)row * DIMS + kb);
        f32x4 a = src[0], b = src[1];
        short8v h;
        #pragma unroll
        for (int e = 0; e < 4; ++e) { h[e] = f16h(a[e]); h[4 + e] = f16h(b[e]); }
        *(short8v*)(Xh + (size_t)G * 4096 + c * 512 + l * 8) = h;
    } else {
        int r = (blockIdx.x - 4096) * 4 + (threadIdx.x >> 6);   // code 0..1023
        int l = threadIdx.x & 63;
        f32x4 v = ((const f32x4*)(embed + (size_t)r * DIMS))[l];
        float s = v[0]*v[0] + v[1]*v[1] + v[2]*v[2] + v[3]*v[3];
        #pragma unroll
        for (int off = 32; off > 0; off >>= 1) s += __shfl_down(s, off, 64);
        if (l == 0) he2[r] = 0.5f * s;
        int G = r >> 4, cc = l >> 3;
        int fl = (r & 15) + 16 * ((l >> 1) & 3);
        size_t base = (size_t)G * 4096 + cc * 512 + fl * 8 + (l & 1) * 4;
        short4v h;
        #pragma unroll
        for (int e = 0; e < 4; ++e) h[e] = f16h(v[e]);
        *(short4v*)(Eh + base) = h;
    }
}

// ---- approx GEMM + argmax(best,2nd): barrier-free per-wave staging -------
// r19 hot loop + block-staggered chunk ring: co-resident blocks start at
// different K-chunks -> their vmcnt(0) waits interleave instead of lockstep.
__global__ __launch_bounds__(256, 4) void vq_mfma(
    const short* __restrict__ Xh, const short* __restrict__ Eh,
    const float* __restrict__ he2, float4* __restrict__ part)
{
    __shared__ char lds[32768];

    const int t = threadIdx.x, lane = t & 63, w = t >> 6;
    const int wm = w >> 1, wn = w & 1;
    const int lhi = lane >> 4, c15 = lane & 15;
    const int sid = blockIdx.x;
    const int xcd = sid & 7, j = sid >> 3;
    const int rb = xcd * 32 + (j >> 3), cb = j & 7;
    const int rowBase = rb * BM, colBase = cb * BN;
    const int st = ((sid >> 8) << 1) & 7;   // chunk-ring start offset

    const char* gA[4];
    const char* gB[4];
    #pragma unroll
    for (int m = 0; m < 4; ++m)
        gA[m] = (const char*)Xh + (size_t)(rb * 8 + wm * 4 + m) * 8192 + lane * 16;
    #pragma unroll
    for (int n = 0; n < 4; ++n)
        gB[n] = (const char*)Eh + (size_t)(cb * 8 + wn * 4 + n) * 8192 + lane * 16;
    char* lw = lds + w * 8192;

    f32x4 acc[4][4];
    #pragma unroll
    for (int m = 0; m < 4; ++m)
        #pragma unroll
        for (int n = 0; n < 4; ++n) acc[m][n] = (f32x4){0.f, 0.f, 0.f, 0.f};

    #pragma unroll
    for (int m = 0; m < 4; ++m) gload_lds16(gA[m] + st * 1024, lw + m * 1024);
    #pragma unroll
    for (int n = 0; n < 4; ++n) gload_lds16(gB[n] + st * 1024, lw + 4096 + n * 1024);

    #pragma unroll
    for (int c = 0; c < 8; ++c) {
        asm volatile("s_waitcnt vmcnt(0)" ::: "memory");   // my chunk arrived
        __builtin_amdgcn_sched_barrier(0);

        half8 A[4], B[4];
        #pragma unroll
        for (int m = 0; m < 4; ++m)
            A[m] = *(const half8*)(lw + m * 1024 + lane * 16);
        #pragma unroll
        for (int n = 0; n < 4; ++n)
            B[n] = *(const half8*)(lw + 4096 + n * 1024 + lane * 16);
        asm volatile("s_waitcnt lgkmcnt(0)" ::: "memory"); // regs loaded
        __builtin_amdgcn_sched_barrier(0);                 // rule #18 fence

        if (c < 7) {                                       // refill in place
            const int nx = (c + 1 + st) & 7;
            #pragma unroll
            for (int m = 0; m < 4; ++m)
                gload_lds16(gA[m] + nx * 1024, lw + m * 1024);
            #pragma unroll
            for (int n = 0; n < 4; ++n)
                gload_lds16(gB[n] + nx * 1024, lw + 4096 + n * 1024);
        }
        __builtin_amdgcn_sched_barrier(0);                 // loads before MFMA

        __builtin_amdgcn_s_setprio(1);
        #pragma unroll
        for (int m = 0; m < 4; ++m)
            #pragma unroll
            for (int n = 0; n < 4; ++n)
                acc[m][n] = __builtin_amdgcn_mfma_f32_16x16x32_f16(A[m], B[n], acc[m][n], 0, 0, 0);
        __builtin_amdgcn_s_setprio(0);
    }

    // ---- epilogue: LDS-assisted best/2nd argmax (verified r16-r19) -------
    __syncthreads();   // all waves done with staging LDS -> safe to alias
    float* S1 = (float*)lds;              // [128][17] f32  (8704 B)
    int*   I1 = (int*)(lds + 8704);       // [128][17] i32
    float* S2 = (float*)(lds + 17408);    // [128][17] f32  (total 26112 B)

    float h2[4];
    #pragma unroll
    for (int n = 0; n < 4; ++n) h2[n] = he2[colBase + 64 * wn + 16 * n + c15];
    const int colg0 = colBase + 64 * wn + c15;

    #pragma unroll
    for (int m = 0; m < 4; ++m) {
        #pragma unroll
        for (int reg = 0; reg < 4; ++reg) {
            float b1 = acc[m][0][reg] - h2[0];
            int   i1 = colg0;
            float b2 = -3.4e38f;
            #pragma unroll
            for (int n = 1; n < 4; ++n) {
                float s = acc[m][n][reg] - h2[n];
                if (s > b1) { b2 = b1; b1 = s; i1 = colg0 + 16 * n; }
                else        { b2 = fmaxf(b2, s); }
            }
            {
                float ob1 = __shfl_xor(b1, 1, 64);
                int   oi1 = __shfl_xor(i1, 1, 64);
                float ob2 = __shfl_xor(b2, 1, 64);
                if (ob1 > b1 || (ob1 == b1 && oi1 < i1)) {
                    b2 = fmaxf(b1, ob2); b1 = ob1; i1 = oi1;
                } else {
                    b2 = fmaxf(b2, ob1);
                }
            }
            if ((c15 & 1) == 0) {
                int row  = 64 * wm + 16 * m + 4 * lhi + reg;   // 0..127
                int slot = wn * 8 + (c15 >> 1);                // 0..15
                S1[row * 17 + slot] = b1;
                I1[row * 17 + slot] = i1;
                S2[row * 17 + slot] = b2;
            }
        }
    }
    __syncthreads();

    if (t < BM) {
        float b1 = S1[t * 17]; int i1 = I1[t * 17]; float b2 = S2[t * 17];
        #pragma unroll
        for (int s = 1; s < 16; ++s) {
            float c1 = S1[t * 17 + s]; int j1 = I1[t * 17 + s];
            float c2 = S2[t * 17 + s];
            if (c1 > b1 || (c1 == b1 && j1 < i1)) { b2 = fmaxf(b1, c2); b1 = c1; i1 = j1; }
            else                                  { b2 = fmaxf(b2, c1); }
        }
        part[(size_t)(rowBase + t) * GY + cb] =
            make_float4(b1, __int_as_float(i1), b2, 0.f);
    }
}

// ---- 16-lane-group exact dot (verified rounds 11-19) ---------------------
__device__ __forceinline__ float dot16(f32x4 xa, f32x4 xb, f32x4 xc, f32x4 xd,
                                       const float* __restrict__ erow, int q) {
    const f32x4* er = (const f32x4*)(erow + q * 16);
    f32x4 ea = er[0], eb = er[1], ec = er[2], ed = er[3];
    float s = xa[0] * ea[0];
    s = fmaf(xa[1], ea[1], s); s = fmaf(xa[2], ea[2], s); s = fmaf(xa[3], ea[3], s);
    s = fmaf(xb[0], eb[0], s); s = fmaf(xb[1], eb[1], s);
    s = fmaf(xb[2], eb[2], s); s = fmaf(xb[3], eb[3], s);
    s = fmaf(xc[0], ec[0], s); s = fmaf(xc[1], ec[1], s);
    s = fmaf(xc[2], ec[2], s); s = fmaf(xc[3], ec[3], s);
    s = fmaf(xd[0], ed[0], s); s = fmaf(xd[1], ed[1], s);
    s = fmaf(xd[2], ed[2], s); s = fmaf(xd[3], ed[3], s);
    s += __shfl_xor(s, 1, 64);
    s += __shfl_xor(s, 2, 64);
    s += __shfl_xor(s, 4, 64);
    s += __shfl_xor(s, 8, 64);
    return s;
}

// ---- combine + gather + fused exact rescue: 16 rows/block, 2048 blocks ---
__global__ __launch_bounds__(256) void vq_combine(
    const float4* __restrict__ part, const float* __restrict__ embed,
    const float* __restrict__ x, const float* __restrict__ he2,
    float* __restrict__ outq, float* __restrict__ outi)
{
    __shared__ int idxS[CROWS];
    __shared__ int flagL[CROWS];
    __shared__ int flagN;
    const int t = threadIdx.x, l = t & 63, w = t >> 6;
    const int rowBase = blockIdx.x * CROWS;

    if (t == 0) flagN = 0;
    __syncthreads();

    if (t < CROWS) {
        const int row = rowBase + t;
        float4 p = part[(size_t)row * GY];
        float b1 = p.x; int i1 = __float_as_int(p.y); float b2 = p.z;
        #pragma unroll
        for (int g = 1; g < GY; ++g) {
            float4 q = part[(size_t)row * GY + g];
            float c1 = q.x; int j1 = __float_as_int(q.y); float c2 = q.z;
            if (c1 > b1 || (c1 == b1 && j1 < i1)) { b2 = fmaxf(b1, c2); b1 = c1; i1 = j1; }
            else                                  { b2 = fmaxf(b2, c1); }
        }
        idxS[t] = i1;
        outi[row] = (float)i1;
        if (b1 - b2 < MARGIN) {
            int s = atomicAdd(&flagN, 1);
            flagL[s] = t;
        }
    }
    __syncthreads();

    #pragma unroll
    for (int qq = 0; qq < (CROWS * 64) / 256; ++qq) {      // 4 iters
        int f = t + 256 * qq;
        int r = f >> 6, c4 = f & 63;
        int e = idxS[r];
        f32x4 v = *(const f32x4*)(embed + (size_t)e * DIMS + c4 * 4);
        *(f32x4*)(outq + (size_t)(rowBase + r) * DIMS + c4 * 4) = v;
    }
    __syncthreads();   // drain approx gather writes before rescue overwrites

    // rescue: one wave per flagged row (verified rounds 11-19)
    const int nf = flagN;
    const int q = l & 15, pgrp = l >> 4;
    for (int it = w; it < nf; it += 4) {
        int rrow = rowBase + flagL[it];
        const f32x4* xr = (const f32x4*)(x + (size_t)rrow * DIMS + q * 16);
        f32x4 xa = xr[0], xb = xr[1], xc = xr[2], xd = xr[3];

        float4 pc[GY];
        #pragma unroll
        for (int g = 0; g < GY; ++g) pc[g] = part[(size_t)rrow * GY + g];
        float B1 = pc[0].x;
        #pragma unroll
        for (int g = 1; g < GY; ++g) B1 = fmaxf(B1, pc[g].x);
        const float T = B1 - MARGIN;

        float wb = -3.4e38f; int wi = 0x7fffffff;
        #pragma unroll
        for (int g = 0; g < GY; ++g) {
            if (pc[g].z >= T) {
                #pragma unroll 2
                for (int i = 0; i < BN / 4; ++i) {
                    int code = g * BN + i * 4 + pgrp;
                    float s = dot16(xa, xb, xc, xd,
                                    embed + (size_t)code * DIMS, q) - he2[code];
                    if (s > wb || (s == wb && code < wi)) { wb = s; wi = code; }
                }
            } else if (pc[g].x >= T) {
                int code = __float_as_int(pc[g].y);
                float s = dot16(xa, xb, xc, xd,
                                embed + (size_t)code * DIMS, q) - he2[code];
                if (s > wb || (s == wb && code < wi)) { wb = s; wi = code; }
            }
        }
        #pragma unroll
        for (int msk = 16; msk <= 32; msk <<= 1) {
            float ob = __shfl_xor(wb, msk, 64);
            int   oi = __shfl_xor(wi, msk, 64);
            if (ob > wb || (ob == wb && oi < wi)) { wb = ob; wi = oi; }
        }
        f32x4 v = ((const f32x4*)(embed + (size_t)wi * DIMS))[l];
        ((f32x4*)(outq + (size_t)rrow * DIMS))[l] = v;
        if (l == 0) outi[rrow] = (float)wi;
    }
}

extern "C" void kernel_launch(void* const* d_in, const int* in_sizes, int n_in,
                              void* d_out, int out_size, void* d_ws, size_t ws_size,
                              hipStream_t stream) {
    const float* x     = (const float*)d_in[0];
    const float* embed = (const float*)d_in[1];
    char* ws = (char*)d_ws;
    float*  he2  = (float*)ws;                              // 4 KB (+pad)
    float4* part = (float4*)(ws + 8192);                    // 4 MB
    short*  Xh   = (short*)(ws + 8192 + 4194304);           // 16.8 MB
    short*  Eh   = (short*)(ws + 8192 + 4194304 + 16777216);// 512 KB
    float*  out  = (float*)d_out;
    float*  outi = out + (size_t)NROWS * DIMS;

    split_all<<<4352, 256, 0, stream>>>(x, Xh, embed, Eh, he2);
    vq_mfma<<<(NROWS / BM) * GY, 256, 0, stream>>>(Xh, Eh, he2, part);
    vq_combine<<<NROWS / CROWS, 256, 0, stream>>>(part, embed, x, he2, out, outi);
}

// Round 22
// 68.952 us; speedup vs baseline: 2.6811x; 1.0513x over previous
//
#include <hip/hip_runtime.h>
#include <stdint.h>

#define NROWS 32768
#define DIMS  256
#define KCB   1024
#define BM 128
#define BN 128
#define GY (KCB/BN)   // 8 code-blocks of 128 cols (part/combine granularity)
#define MARGIN 0.25f  // flag threshold AND rescue candidate window
#define CROWS 16      // rows per combine block

typedef _Float16 half8   __attribute__((ext_vector_type(8)));
typedef float    f32x4   __attribute__((ext_vector_type(4)));
typedef short    short4v __attribute__((ext_vector_type(4)));
typedef short    short8v __attribute__((ext_vector_type(8)));

// async global->LDS, 16B per lane; LDS dest = wave-uniform base + lane*16
__device__ __forceinline__ void gload_lds16(const void* g, void* l) {
    __builtin_amdgcn_global_load_lds(
        (const __attribute__((address_space(1))) uint32_t*)g,
        (__attribute__((address_space(3))) uint32_t*)l, 16, 0, 0);
}

__device__ __forceinline__ short f16h(float v) {
    _Float16 hh = (_Float16)v;
    return __builtin_bit_cast(short, hh);
}

// ---- merged splitter: X and E -> fragment-ordered f16 + he2 --------------
__global__ __launch_bounds__(256) void split_all(
    const float* __restrict__ x, short* __restrict__ Xh,
    const float* __restrict__ embed, short* __restrict__ Eh,
    float* __restrict__ he2)
{
    if (blockIdx.x < 4096) {
        int T = blockIdx.x * 256 + threadIdx.x;
        int l = T & 63, c = (T >> 6) & 7, G = T >> 9;
        int row = G * 16 + (l & 15);
        int kb  = c * 32 + (l >> 4) * 8;
        const f32x4* src = (const f32x4*)(x + (size_t)row * DIMS + kb);
        f32x4 a = src[0], b = src[1];
        short8v h;
        #pragma unroll
        for (int e = 0; e < 4; ++e) { h[e] = f16h(a[e]); h[4 + e] = f16h(b[e]); }
        *(short8v*)(Xh + (size_t)G * 4096 + c * 512 + l * 8) = h;
    } else {
        int r = (blockIdx.x - 4096) * 4 + (threadIdx.x >> 6);   // code 0..1023
        int l = threadIdx.x & 63;
        f32x4 v = ((const f32x4*)(embed + (size_t)r * DIMS))[l];
        float s = v[0]*v[0] + v[1]*v[1] + v[2]*v[2] + v[3]*v[3];
        #pragma unroll
        for (int off = 32; off > 0; off >>= 1) s += __shfl_down(s, off, 64);
        if (l == 0) he2[r] = 0.5f * s;
        int G = r >> 4, cc = l >> 3;
        int fl = (r & 15) + 16 * ((l >> 1) & 3);
        size_t base = (size_t)G * 4096 + cc * 512 + fl * 8 + (l & 1) * 4;
        short4v h;
        #pragma unroll
        for (int e = 0; e < 4; ++e) h[e] = f16h(v[e]);
        *(short4v*)(Eh + base) = h;
    }
}

// ---- approx GEMM + argmax(best,2nd): barrier-free, 128x256 block tile ----
// Wave = 64 rows x 128 cols: A 4 frags + B 8 frags = 12KB/wave, 32 MFMA per
// latency exposure (2x r19's intensity); grid halves to 1024. part output
// stays per-128-col (entry cbb*2+wn) so combine/rescue are unchanged.
__global__ __launch_bounds__(256, 2) void vq_mfma(
    const short* __restrict__ Xh, const short* __restrict__ Eh,
    const float* __restrict__ he2, float4* __restrict__ part)
{
    __shared__ char lds[49152];

    const int t = threadIdx.x, lane = t & 63, w = t >> 6;
    const int wm = w >> 1, wn = w & 1;
    const int lhi = lane >> 4, c15 = lane & 15;
    const int sid = blockIdx.x;
    const int xcd = sid & 7, j = sid >> 3;          // j: 0..127
    const int rb = xcd * 32 + (j >> 2), cbb = j & 3;
    const int rowBase = rb * BM, colBase = cbb * 256;

    const char* gA[4];
    const char* gB[8];
    #pragma unroll
    for (int m = 0; m < 4; ++m)
        gA[m] = (const char*)Xh + (size_t)(rb * 8 + wm * 4 + m) * 8192 + lane * 16;
    #pragma unroll
    for (int n = 0; n < 8; ++n)
        gB[n] = (const char*)Eh + (size_t)(cbb * 16 + wn * 8 + n) * 8192 + lane * 16;
    char* lw = lds + w * 12288;

    f32x4 acc[4][8];
    #pragma unroll
    for (int m = 0; m < 4; ++m)
        #pragma unroll
        for (int n = 0; n < 8; ++n) acc[m][n] = (f32x4){0.f, 0.f, 0.f, 0.f};

    #pragma unroll
    for (int m = 0; m < 4; ++m) gload_lds16(gA[m], lw + m * 1024);
    #pragma unroll
    for (int n = 0; n < 8; ++n) gload_lds16(gB[n], lw + 4096 + n * 1024);

    #pragma unroll
    for (int c = 0; c < 8; ++c) {
        asm volatile("s_waitcnt vmcnt(0)" ::: "memory");   // my chunk arrived
        __builtin_amdgcn_sched_barrier(0);

        half8 A[4], B[8];
        #pragma unroll
        for (int m = 0; m < 4; ++m)
            A[m] = *(const half8*)(lw + m * 1024 + lane * 16);
        #pragma unroll
        for (int n = 0; n < 8; ++n)
            B[n] = *(const half8*)(lw + 4096 + n * 1024 + lane * 16);
        asm volatile("s_waitcnt lgkmcnt(0)" ::: "memory"); // regs loaded
        __builtin_amdgcn_sched_barrier(0);                 // rule #18 fence

        if (c < 7) {                                       // refill in place
            #pragma unroll
            for (int m = 0; m < 4; ++m)
                gload_lds16(gA[m] + (c + 1) * 1024, lw + m * 1024);
            #pragma unroll
            for (int n = 0; n < 8; ++n)
                gload_lds16(gB[n] + (c + 1) * 1024, lw + 4096 + n * 1024);
        }
        __builtin_amdgcn_sched_barrier(0);                 // loads before MFMA

        __builtin_amdgcn_s_setprio(1);
        #pragma unroll
        for (int m = 0; m < 4; ++m)
            #pragma unroll
            for (int n = 0; n < 8; ++n)
                acc[m][n] = __builtin_amdgcn_mfma_f32_16x16x32_f16(A[m], B[n], acc[m][n], 0, 0, 0);
        __builtin_amdgcn_s_setprio(0);
    }

    // ---- epilogue: LDS-assisted best/2nd argmax, per-128-col partials ----
    __syncthreads();   // all waves done with staging LDS -> safe to alias
    float* S1 = (float*)lds;              // [128][18] f32  (9216 B)
    int*   I1 = (int*)(lds + 9216);       // [128][18] i32
    float* S2 = (float*)(lds + 18432);    // [128][18] f32  (total 27648 B)

    float h2[8];
    #pragma unroll
    for (int n = 0; n < 8; ++n)
        h2[n] = he2[colBase + wn * 128 + 16 * n + c15];
    const int colg0 = colBase + wn * 128 + c15;

    #pragma unroll
    for (int m = 0; m < 4; ++m) {
        #pragma unroll
        for (int reg = 0; reg < 4; ++reg) {
            float b1 = acc[m][0][reg] - h2[0];
            int   i1 = colg0;
            float b2 = -3.4e38f;
            #pragma unroll
            for (int n = 1; n < 8; ++n) {
                float s = acc[m][n][reg] - h2[n];
                if (s > b1) { b2 = b1; b1 = s; i1 = colg0 + 16 * n; }
                else        { b2 = fmaxf(b2, s); }
            }
            {
                float ob1 = __shfl_xor(b1, 1, 64);
                int   oi1 = __shfl_xor(i1, 1, 64);
                float ob2 = __shfl_xor(b2, 1, 64);
                if (ob1 > b1 || (ob1 == b1 && oi1 < i1)) {
                    b2 = fmaxf(b1, ob2); b1 = ob1; i1 = oi1;
                } else {
                    b2 = fmaxf(b2, ob1);
                }
            }
            if ((c15 & 1) == 0) {
                int row  = 64 * wm + 16 * m + 4 * lhi + reg;   // 0..127
                int slot = wn * 9 + (c15 >> 1);                // wn-half, 8 slots
                S1[row * 18 + slot] = b1;
                I1[row * 18 + slot] = i1;
                S2[row * 18 + slot] = b2;
            }
        }
    }
    __syncthreads();

    {   // t<256: ww = col-half, tt = row; merge that half's 8 slots
        const int ww = t >> 7, tt = t & 127;
        float b1 = S1[tt * 18 + ww * 9]; int i1 = I1[tt * 18 + ww * 9];
        float b2 = S2[tt * 18 + ww * 9];
        #pragma unroll
        for (int s = 1; s < 8; ++s) {
            float c1 = S1[tt * 18 + ww * 9 + s]; int j1 = I1[tt * 18 + ww * 9 + s];
            float c2 = S2[tt * 18 + ww * 9 + s];
            if (c1 > b1 || (c1 == b1 && j1 < i1)) { b2 = fmaxf(b1, c2); b1 = c1; i1 = j1; }
            else                                  { b2 = fmaxf(b2, c1); }
        }
        part[(size_t)(rowBase + tt) * GY + cbb * 2 + ww] =
            make_float4(b1, __int_as_float(i1), b2, 0.f);
    }
}

// ---- 16-lane-group exact dot (verified rounds 11-21) ---------------------
__device__ __forceinline__ float dot16(f32x4 xa, f32x4 xb, f32x4 xc, f32x4 xd,
                                       const float* __restrict__ erow, int q) {
    const f32x4* er = (const f32x4*)(erow + q * 16);
    f32x4 ea = er[0], eb = er[1], ec = er[2], ed = er[3];
    float s = xa[0] * ea[0];
    s = fmaf(xa[1], ea[1], s); s = fmaf(xa[2], ea[2], s); s = fmaf(xa[3], ea[3], s);
    s = fmaf(xb[0], eb[0], s); s = fmaf(xb[1], eb[1], s);
    s = fmaf(xb[2], eb[2], s); s = fmaf(xb[3], eb[3], s);
    s = fmaf(xc[0], ec[0], s); s = fmaf(xc[1], ec[1], s);
    s = fmaf(xc[2], ec[2], s); s = fmaf(xc[3], ec[3], s);
    s = fmaf(xd[0], ed[0], s); s = fmaf(xd[1], ed[1], s);
    s = fmaf(xd[2], ed[2], s); s = fmaf(xd[3], ed[3], s);
    s += __shfl_xor(s, 1, 64);
    s += __shfl_xor(s, 2, 64);
    s += __shfl_xor(s, 4, 64);
    s += __shfl_xor(s, 8, 64);
    return s;
}

// ---- combine + gather + fused exact rescue: 16 rows/block, 2048 blocks ---
__global__ __launch_bounds__(256) void vq_combine(
    const float4* __restrict__ part, const float* __restrict__ embed,
    const float* __restrict__ x, const float* __restrict__ he2,
    float* __restrict__ outq, float* __restrict__ outi)
{
    __shared__ int idxS[CROWS];
    __shared__ int flagL[CROWS];
    __shared__ int flagN;
    const int t = threadIdx.x, l = t & 63, w = t >> 6;
    const int rowBase = blockIdx.x * CROWS;

    if (t == 0) flagN = 0;
    __syncthreads();

    if (t < CROWS) {
        const int row = rowBase + t;
        float4 p = part[(size_t)row * GY];
        float b1 = p.x; int i1 = __float_as_int(p.y); float b2 = p.z;
        #pragma unroll
        for (int g = 1; g < GY; ++g) {
            float4 q = part[(size_t)row * GY + g];
            float c1 = q.x; int j1 = __float_as_int(q.y); float c2 = q.z;
            if (c1 > b1 || (c1 == b1 && j1 < i1)) { b2 = fmaxf(b1, c2); b1 = c1; i1 = j1; }
            else                                  { b2 = fmaxf(b2, c1); }
        }
        idxS[t] = i1;
        outi[row] = (float)i1;
        if (b1 - b2 < MARGIN) {
            int s = atomicAdd(&flagN, 1);
            flagL[s] = t;
        }
    }
    __syncthreads();

    #pragma unroll
    for (int qq = 0; qq < (CROWS * 64) / 256; ++qq) {      // 4 iters
        int f = t + 256 * qq;
        int r = f >> 6, c4 = f & 63;
        int e = idxS[r];
        f32x4 v = *(const f32x4*)(embed + (size_t)e * DIMS + c4 * 4);
        *(f32x4*)(outq + (size_t)(rowBase + r) * DIMS + c4 * 4) = v;
    }
    __syncthreads();   // drain approx gather writes before rescue overwrites

    // rescue: one wave per flagged row (verified rounds 11-21)
    const int nf = flagN;
    const int q = l & 15, pgrp = l >> 4;
    for (int it = w; it < nf; it += 4) {
        int rrow = rowBase + flagL[it];
        const f32x4* xr = (const f32x4*)(x + (size_t)rrow * DIMS + q * 16);
        f32x4 xa = xr[0], xb = xr[1], xc = xr[2], xd = xr[3];

        float4 pc[GY];
        #pragma unroll
        for (int g = 0; g < GY; ++g) pc[g] = part[(size_t)rrow * GY + g];
        float B1 = pc[0].x;
        #pragma unroll
        for (int g = 1; g < GY; ++g) B1 = fmaxf(B1, pc[g].x);
        const float T = B1 - MARGIN;

        float wb = -3.4e38f; int wi = 0x7fffffff;
        #pragma unroll
        for (int g = 0; g < GY; ++g) {
            if (pc[g].z >= T) {
                #pragma unroll 2
                for (int i = 0; i < BN / 4; ++i) {
                    int code = g * BN + i * 4 + pgrp;
                    float s = dot16(xa, xb, xc, xd,
                                    embed + (size_t)code * DIMS, q) - he2[code];
                    if (s > wb || (s == wb && code < wi)) { wb = s; wi = code; }
                }
            } else if (pc[g].x >= T) {
                int code = __float_as_int(pc[g].y);
                float s = dot16(xa, xb, xc, xd,
                                embed + (size_t)code * DIMS, q) - he2[code];
                if (s > wb || (s == wb && code < wi)) { wb = s; wi = code; }
            }
        }
        #pragma unroll
        for (int msk = 16; msk <= 32; msk <<= 1) {
            float ob = __shfl_xor(wb, msk, 64);
            int   oi = __shfl_xor(wi, msk, 64);
            if (ob > wb || (ob == wb && oi < wi)) { wb = ob; wi = oi; }
        }
        f32x4 v = ((const f32x4*)(embed + (size_t)wi * DIMS))[l];
        ((f32x4*)(outq + (size_t)rrow * DIMS))[l] = v;
        if (l == 0) outi[rrow] = (float)wi;
    }
}

extern "C" void kernel_launch(void* const* d_in, const int* in_sizes, int n_in,
                              void* d_out, int out_size, void* d_ws, size_t ws_size,
                              hipStream_t stream) {
    const float* x     = (const float*)d_in[0];
    const float* embed = (const float*)d_in[1];
    char* ws = (char*)d_ws;
    float*  he2  = (float*)ws;                              // 4 KB (+pad)
    float4* part = (float4*)(ws + 8192);                    // 4 MB
    short*  Xh   = (short*)(ws + 8192 + 4194304);           // 16.8 MB
    short*  Eh   = (short*)(ws + 8192 + 4194304 + 16777216);// 512 KB
    float*  out  = (float*)d_out;
    float*  outi = out + (size_t)NROWS * DIMS;

    split_all<<<4352, 256, 0, stream>>>(x, Xh, embed, Eh, he2);
    vq_mfma<<<256 * 4, 256, 0, stream>>>(Xh, Eh, he2, part);
    vq_combine<<<NROWS / CROWS, 256, 0, stream>>>(part, embed, x, he2, out, outi);
}